// Round 7
// baseline (17538.881 us; speedup 1.0000x reference)
//
#include <hip/hip_runtime.h>
#include <math.h>

#define NU 512     // hidden units
#define BT 128     // batch
#define TT 1024    // timesteps
#define ID 128     // input dim
#define OC 10      // out classes
#define NGRP 32    // pair-groups; cohort A rows [2g,2g+2), B rows [64+2g,64+2g+2)
#define CWG 8      // WGs per group (col slices)
#define JCOL 64    // cols per WG
#define THREADS 512

static constexpr float F_EPS = 0.01f;
static constexpr float F_CT  = -0.6f;   // coefficient of B^T / C^T (beta=0.8)
static constexpr float F_GAM = 0.01f;

// ws layout (floats): h0 [0,65536) | h1 [65536,131072)
// ints at float-index 131072: cntA[32] | cntB[32]  (monotonic counters)
#define WS_H1  65536
#define WS_CNT 131072

// LDS (dwords): per cohort: h stage [2][544] skewed; x dbuf 2 x [2][160].
// Skew: (r,k) -> r*544 + k + (k>>6)*4 ; (r,i) -> r*160 + i + (i>>4)*4
#define OFF_HA  0
#define OFF_HB  1088
#define OFF_XA0 2176
#define OFF_XA1 2496
#define OFF_XB0 2816
#define OFF_XB1 3136
// Pad dynamic LDS to 96 KB: forces exactly 1 WG/CU so all 256 WGs are
// co-resident -> the inter-WG counter barrier cannot deadlock.
#define LDS_BYTES 98304

typedef float f32x4 __attribute__((ext_vector_type(4)));
typedef float f32x2 __attribute__((ext_vector_type(2)));

__global__ void init_kernel(float* ws) {
    int i = blockIdx.x * 256 + threadIdx.x;   // 65536 threads
    if (i < BT * NU) ws[i] = 0.0f;            // zero h0
    int* cnt = (int*)(ws + WS_CNT);
    if (i < 2 * NGRP) cnt[i] = 0;             // zero monotonic counters
}

// One cohort phase of one timestep. All primitives identical to the
// round-4-verified kernel: asm coherent load (sc0 sc1), agent-scope
// atomic store/add via __hip_atomic_* (compiler-visible -> drained before
// s_barrier), tid0-only poll with s_sleep backoff, full barriers.
__device__ __forceinline__ void run_phase(
    int t, const float* __restrict__ x, const float* hin, float* hout,
    int* cnt, float* sm, int offH, int offXc, int offXn,
    const f32x2 (&rA)[32], const f32x2 (&rW)[32], const f32x2 (&rE)[8],
    float ebv, int row0, int tid, int kc, int cg)
{
    // gate: producers of hin (step t-1 of this cohort) all flagged
    if (t > 0) {
        if (tid == 0) {
            const int need = CWG * t;
            while (__hip_atomic_load(cnt, __ATOMIC_RELAXED,
                                     __HIP_MEMORY_SCOPE_AGENT) < need)
                __builtin_amdgcn_s_sleep(1);
        }
        __syncthreads();
    }

    // issue coherent h load (8B per thread), do NOT wait yet
    f32x2 hvv;
    const int sr = tid >> 8;            // row 0..1
    const int sk = (tid & 255) * 2;     // dword pair base
    {
        const float* hsrc = hin + (size_t)(row0 + sr) * NU + sk;
        asm volatile("global_load_dwordx2 %0, %1, off sc0 sc1"
                     : "=v"(hvv) : "v"(hsrc));
    }
    // x prefetch for t+1 (plain cached load; x is read-only input)
    float xvr = 0.0f;
    const int xr_ = tid >> 7, xe = tid & 127;   // valid for tid<256
    if (tid < 256 && t + 1 < TT)
        xvr = x[(size_t)(row0 + xr_) * TT * ID + (size_t)(t + 1) * ID + xe];

    // z partials from current x buffer — overlaps the h-load latency
    f32x2 zac[2];
    #pragma unroll
    for (int r = 0; r < 2; ++r) {
        zac[r] = (f32x2){0.f, 0.f};
        const float* xr = sm + offXc + r * 160 + kc * 20;
        #pragma unroll
        for (int q = 0; q < 4; ++q) {
            f32x4 xv = *(const f32x4*)(xr + q * 4);
            f32x2 xlo = __builtin_shufflevector(xv, xv, 0, 1);
            f32x2 xhi = __builtin_shufflevector(xv, xv, 2, 3);
            zac[r] = __builtin_elementwise_fma(xlo, rE[2 * q], zac[r]);
            zac[r] = __builtin_elementwise_fma(xhi, rE[2 * q + 1], zac[r]);
        }
    }

    // wait for h (and x), publish to LDS
    asm volatile("s_waitcnt vmcnt(0)" : "+v"(hvv) :: "memory");
    *(f32x2*)(sm + offH + sr * 544 + sk + (sk >> 6) * 4) = hvv;
    if (tid < 256 && t + 1 < TT)
        sm[offXn + xr_ * 160 + xe + (xe >> 4) * 4] = xvr;
    __syncthreads();

    // h @ A and h @ W partials over this thread's 64 k (weights in VGPRs)
    f32x2 aA[2], aW[2];
    #pragma unroll
    for (int r = 0; r < 2; ++r) {
        aA[r] = (f32x2){0.f, 0.f};
        aW[r] = zac[r];
        const float* hr = sm + offH + r * 544 + kc * 68;
        #pragma unroll
        for (int q = 0; q < 16; ++q) {
            f32x4 hv = *(const f32x4*)(hr + q * 4);
            f32x2 hlo = __builtin_shufflevector(hv, hv, 0, 1);
            f32x2 hhi = __builtin_shufflevector(hv, hv, 2, 3);
            aA[r] = __builtin_elementwise_fma(hlo, rA[2 * q], aA[r]);
            aW[r] = __builtin_elementwise_fma(hlo, rW[2 * q], aW[r]);
            aA[r] = __builtin_elementwise_fma(hhi, rA[2 * q + 1], aA[r]);
            aW[r] = __builtin_elementwise_fma(hhi, rW[2 * q + 1], aW[r]);
        }
    }

    // collapse f32x2 -> scalar, butterfly over kc (lane bits 3..5)
    float sA[2], sW[2];
    #pragma unroll
    for (int r = 0; r < 2; ++r) {
        sA[r] = aA[r][0] + aA[r][1];
        sW[r] = aW[r][0] + aW[r][1];
    }
    #pragma unroll
    for (int m = 8; m <= 32; m <<= 1) {
        #pragma unroll
        for (int r = 0; r < 2; ++r) {
            sA[r] += __shfl_xor(sA[r], m, 64);
            sW[r] += __shfl_xor(sW[r], m, 64);
        }
    }

    // lane-group kc==r owns row r: one tanh + one agent-scope store
    if (kc < 2) {
        const int r = kc;
        float hold = sm[offH + r * 544 + cg + (cg >> 6) * 4];
        float hnew = hold + F_EPS * sA[r] + F_EPS * tanhf(sW[r] + ebv);
        __hip_atomic_store(hout + (size_t)(row0 + r) * NU + cg, hnew,
                           __ATOMIC_RELAXED, __HIP_MEMORY_SCOPE_AGENT);
    }
    __syncthreads();   // compiler drains vmcnt before s_barrier -> stores visible
    if (tid == 0)
        __hip_atomic_fetch_add(cnt, 1, __ATOMIC_RELEASE,
                               __HIP_MEMORY_SCOPE_AGENT);
    // flag propagation overlaps the other cohort's phase
}

__global__ __launch_bounds__(THREADS, 2)
void scan_kernel(const float* __restrict__ x, const float* __restrict__ B,
                 const float* __restrict__ C, const float* __restrict__ Ew,
                 const float* __restrict__ Eb, float* ws)
{
    extern __shared__ float sm[];
    const int tid = threadIdx.x;
    const int bid = blockIdx.x;
    const int g = bid & (NGRP - 1);   // pair-group
    const int slice = bid >> 5;       // col slice 0..7
    const int jbase = slice * JCOL;
    const int row0A = g * 2;          // cohort A rows
    const int row0B = 64 + g * 2;     // cohort B rows

    float* h0 = ws;
    float* h1 = ws + WS_H1;
    int* cntA = (int*)(ws + WS_CNT) + g;
    int* cntB = cntA + NGRP;

    // compute mapping: wave w -> 8 cols; lane = kc*8 + jl; kc = 8-way k split
    const int lane = tid & 63;
    const int w = tid >> 6;
    const int jl = lane & 7;
    const int kc = lane >> 3;
    const int cg = jbase + w * 8 + jl;     // this thread's global column
    const int k0 = kc * 64;                // this thread's k range [k0, k0+64)

    // ---- register-resident weights (constant across all 1024 steps) ----
    f32x2 rA[32], rW[32], rE[8];
    #pragma unroll
    for (int u2 = 0; u2 < 32; ++u2) {
        #pragma unroll
        for (int p = 0; p < 2; ++p) {
            int k = k0 + 2 * u2 + p;
            float dia = (k == cg) ? F_GAM : 0.0f;
            rA[u2][p] = B[(size_t)k * NU + cg] + F_CT * B[(size_t)cg * NU + k] - dia;
            rW[u2][p] = C[(size_t)k * NU + cg] + F_CT * C[(size_t)cg * NU + k] - dia;
        }
    }
    #pragma unroll
    for (int v2 = 0; v2 < 8; ++v2) {
        rE[v2][0] = Ew[(size_t)(kc * 16 + 2 * v2) * NU + cg];
        rE[v2][1] = Ew[(size_t)(kc * 16 + 2 * v2 + 1) * NU + cg];
    }
    const float ebv = Eb[cg];

    // prologue: stage x(t=0) for both cohorts
    {
        int t2 = tid & 255;
        int xr_ = t2 >> 7, xe = t2 & 127;
        int xp = xr_ * 160 + xe + (xe >> 4) * 4;
        if (tid < 256)
            sm[OFF_XA0 + xp] = x[(size_t)(row0A + xr_) * TT * ID + xe];
        else
            sm[OFF_XB0 + xp] = x[(size_t)(row0B + xr_) * TT * ID + xe];
    }
    __syncthreads();

    for (int t = 0; t < TT; ++t) {
        const float* hin = (t & 1) ? h1 : h0;
        float* hout = (t & 1) ? h0 : h1;
        const int xaC = (t & 1) ? OFF_XA1 : OFF_XA0;
        const int xaN = (t & 1) ? OFF_XA0 : OFF_XA1;
        const int xbC = (t & 1) ? OFF_XB1 : OFF_XB0;
        const int xbN = (t & 1) ? OFF_XB0 : OFF_XB1;

        run_phase(t, x, hin, hout, cntA, sm, OFF_HA, xaC, xaN,
                  rA, rW, rE, ebv, row0A, tid, kc, cg);
        run_phase(t, x, hin, hout, cntB, sm, OFF_HB, xbC, xbN,
                  rA, rW, rE, ebv, row0B, tid, kc, cg);
    }
}

__global__ void head_kernel(const float* __restrict__ ws, const float* __restrict__ Dw,
                            const float* __restrict__ Db, float* __restrict__ out)
{
    __shared__ float red2[32][16];
    int b = blockIdx.x;
    int tid = threadIdx.x;        // 512
    int j = tid & 15;
    int kc = tid >> 4;            // 0..31, 16 k each
    const float* h = ws + (size_t)b * NU;   // final h lives in h0 (TT even)
    float acc = 0.0f;
    if (j < OC) {
        for (int u = 0; u < 16; ++u) {
            int k = kc * 16 + u;
            acc += h[k] * Dw[(size_t)k * OC + j];
        }
    }
    red2[kc][j] = acc;
    __syncthreads();
    if (kc == 0 && j < OC) {
        float s = 0.0f;
        #pragma unroll
        for (int u = 0; u < 32; ++u) s += red2[u][j];
        out[(size_t)b * OC + j] = s + Db[j];
    }
}

extern "C" void kernel_launch(void* const* d_in, const int* in_sizes, int n_in,
                              void* d_out, int out_size, void* d_ws, size_t ws_size,
                              hipStream_t stream) {
    const float* x  = (const float*)d_in[0];
    const float* B  = (const float*)d_in[1];
    const float* C  = (const float*)d_in[2];
    const float* Ew = (const float*)d_in[3];
    const float* Eb = (const float*)d_in[4];
    const float* Dw = (const float*)d_in[5];
    const float* Db = (const float*)d_in[6];
    float* ws  = (float*)d_ws;
    float* out = (float*)d_out;

    (void)hipFuncSetAttribute((const void*)scan_kernel,
                              hipFuncAttributeMaxDynamicSharedMemorySize, LDS_BYTES);

    init_kernel<<<256, 256, 0, stream>>>(ws);
    scan_kernel<<<NGRP * CWG, THREADS, LDS_BYTES, stream>>>(x, B, C, Ew, Eb, ws);
    head_kernel<<<BT, THREADS, 0, stream>>>(ws, Dw, Db, out);
}